// Round 1
// baseline (97016.840 us; speedup 1.0000x reference)
//
#include <hip/hip_runtime.h>

#define VOCABN 401
#define EN 256
#define HN 768
#define H3N 2304
#define ON 3
#define BN 64
#define TN 1024

typedef _Float16 f16x2 __attribute__((ext_vector_type(2)));
typedef _Float16 f16x8 __attribute__((ext_vector_type(8)));

union F16x8 { f16x8 v; f16x2 p[4]; };

__device__ __forceinline__ float fdot2(f16x2 a, f16x2 b, float c) {
#if __has_builtin(__builtin_amdgcn_fdot2)
    return __builtin_amdgcn_fdot2(a, b, c, false);
#else
    return c + (float)a[0] * (float)b[0] + (float)a[1] * (float)b[1];
#endif
}

// ---------------- K0: convert W_hh (f32 row-major [2304][768]) -> f16 same layout
__global__ void k_convert_whh(const float* __restrict__ whh, _Float16* __restrict__ w16) {
    int i = blockIdx.x * 256 + threadIdx.x;
    if (i < H3N * HN) w16[i] = (_Float16)whh[i];
}

// ---------------- K1: G[v][g] = sum_e embed[v][e] * W_ih[g][e] + b_ih[g]   (f32 table)
__global__ void k_build_gtab(const float* __restrict__ embed, const float* __restrict__ wih,
                             const float* __restrict__ bih, float* __restrict__ gtab) {
    int v = blockIdx.y;
    int g = blockIdx.x * 256 + threadIdx.x;   // 0..2303
    __shared__ float ev[EN];
    if (threadIdx.x < EN) ev[threadIdx.x] = embed[v * EN + threadIdx.x];
    __syncthreads();
    const float4* w4 = (const float4*)(wih + (size_t)g * EN);
    const float4* e4 = (const float4*)ev;
    float acc = bih[g];
#pragma unroll 8
    for (int i = 0; i < EN / 4; ++i) {
        float4 w = w4[i], e = e4[i];
        acc += w.x * e.x + w.y * e.y + w.z * e.z + w.w * e.w;
    }
    gtab[(size_t)v * H3N + g] = acc;
}

// ---------------- K2: the recurrence. one workgroup per batch, 768 threads.
// thread j owns h[j]; per step computes rows j, 768+j, 1536+j of W_hh @ h.
__launch_bounds__(768, 1)
__global__ void k_rnn(const int* __restrict__ tokens, const _Float16* __restrict__ w16,
                      const float* __restrict__ gtab, const float* __restrict__ bhh,
                      float* __restrict__ hout) {
    const int b = blockIdx.x;
    const int j = threadIdx.x;

    __shared__ __align__(16) _Float16 h16[HN];  // shared f16 copy of h state
    __shared__ int stok[TN];

    h16[j] = (_Float16)0.f;
    for (int i = j; i < TN; i += HN) stok[i] = tokens[b * TN + i];

    const float bhr = bhh[j], bhz = bhh[HN + j], bhn = bhh[2 * HN + j];
    const f16x8* wr8 = (const f16x8*)(w16 + (size_t)j * HN);
    const f16x8* wz8 = (const f16x8*)(w16 + (size_t)(HN + j) * HN);
    const f16x8* wn8 = (const f16x8*)(w16 + (size_t)(2 * HN + j) * HN);
    const f16x8* h8  = (const f16x8*)h16;

    float hprev = 0.f;  // this thread's own h[j], kept in f32
    __syncthreads();

    for (int t = 0; t < TN; ++t) {
        const int tok = stok[t];
        const float* gr = gtab + (size_t)tok * H3N;
        // issue the (random-row) x loads early; they complete during the dot loop
        const float xr = gr[j], xz = gr[HN + j], xn = gr[2 * HN + j];

        float ar = bhr, az = bhz, an = bhn;
#pragma unroll 4
        for (int i = 0; i < HN / 8; ++i) {
            F16x8 wr, wz, wn, hh;
            wr.v = wr8[i]; wz.v = wz8[i]; wn.v = wn8[i]; hh.v = h8[i];
#pragma unroll
            for (int q = 0; q < 4; ++q) {
                ar = fdot2(wr.p[q], hh.p[q], ar);
                az = fdot2(wz.p[q], hh.p[q], az);
                an = fdot2(wn.p[q], hh.p[q], an);
            }
        }

        const float r = 1.f / (1.f + __expf(-(xr + ar)));
        const float z = 1.f / (1.f + __expf(-(xz + az)));
        const float nx = xn + r * an;
        const float n = 1.f - 2.f / (__expf(2.f * nx) + 1.f);  // tanh(nx)
        const float hnew = (1.f - z) * n + z * hprev;

        __syncthreads();                 // everyone done reading old h16
        h16[j] = (_Float16)hnew;
        hprev = hnew;
        __syncthreads();                 // new h16 visible
    }
    hout[(size_t)b * HN + j] = hprev;
}

// ---------------- K3: logits + log_softmax. one block per batch, 3 waves (one per output).
__global__ void k_logits(const float* __restrict__ hfin, const float* __restrict__ wout,
                         const float* __restrict__ bout, float* __restrict__ lp) {
    const int b = blockIdx.x;
    const int o = threadIdx.x / 64;
    const int lane = threadIdx.x % 64;
    const float* hrow = hfin + (size_t)b * HN;
    const float* w = wout + (size_t)o * HN;
    float p = 0.f;
    for (int k = lane; k < HN; k += 64) p += hrow[k] * w[k];
    for (int off = 32; off > 0; off >>= 1) p += __shfl_down(p, off, 64);
    __shared__ float lg[ON];
    if (lane == 0) lg[o] = p + bout[o];
    __syncthreads();
    if (threadIdx.x == 0) {
        float m = fmaxf(lg[0], fmaxf(lg[1], lg[2]));
        float s = __expf(lg[0] - m) + __expf(lg[1] - m) + __expf(lg[2] - m);
        float ls = __logf(s);
        lp[b * ON + 0] = lg[0] - m - ls;
        lp[b * ON + 1] = lg[1] - m - ls;
        lp[b * ON + 2] = lg[2] - m - ls;
    }
}

extern "C" void kernel_launch(void* const* d_in, const int* in_sizes, int n_in,
                              void* d_out, int out_size, void* d_ws, size_t ws_size,
                              hipStream_t stream) {
    const int*   tokens = (const int*)d_in[0];
    // d_in[1] = hidden: reference zeroes it, ignored.
    const float* embed  = (const float*)d_in[2];
    const float* wih    = (const float*)d_in[3];
    const float* whh    = (const float*)d_in[4];
    const float* bih    = (const float*)d_in[5];
    const float* bhh    = (const float*)d_in[6];
    const float* wout   = (const float*)d_in[7];
    const float* bout   = (const float*)d_in[8];

    float* out = (float*)d_out;           // [B*O logprobs][B*H h_final]
    char* ws = (char*)d_ws;
    float*    gtab = (float*)ws;                       // 401*2304*4  = 3,695,616 B
    _Float16* w16  = (_Float16*)(ws + 3700736);        // 2304*768*2  = 3,538,944 B

    hipLaunchKernelGGL(k_convert_whh, dim3((H3N * HN + 255) / 256), dim3(256), 0, stream,
                       whh, w16);
    hipLaunchKernelGGL(k_build_gtab, dim3(H3N / 256, VOCABN), dim3(256), 0, stream,
                       embed, wih, bih, gtab);
    hipLaunchKernelGGL(k_rnn, dim3(BN), dim3(HN), 0, stream,
                       tokens, w16, gtab, bhh, out + BN * ON);
    hipLaunchKernelGGL(k_logits, dim3(BN), dim3(192), 0, stream,
                       out + BN * ON, wout, bout, out);
}

// Round 2
// 18784.525 us; speedup vs baseline: 5.1647x; 5.1647x over previous
//
#include <hip/hip_runtime.h>

#define VOCABN 401
#define EN 256
#define HN 768
#define H3N 2304
#define ON 3
#define BN 64
#define TN 1024

// replica geometry: 16 replicas x 16 WGs; each WG: 48 j's, k split 8 ways, 4 batches
#define NREP 16
#define WGPR 16
#define BPR  4
#define JPW  48
#define NTH  384   // JPW * 8

typedef _Float16 f16x2 __attribute__((ext_vector_type(2)));
typedef _Float16 f16x8 __attribute__((ext_vector_type(8)));

union F16x8 { f16x8 v; f16x2 p[4]; };

__device__ __forceinline__ float fdot2(f16x2 a, f16x2 b, float c) {
#if __has_builtin(__builtin_amdgcn_fdot2)
    return __builtin_amdgcn_fdot2(a, b, c, false);
#else
    return c + (float)a[0] * (float)b[0] + (float)a[1] * (float)b[1];
#endif
}

// ---------------- K1: G[v][g] = sum_e embed[v][e] * W_ih[g][e] + b_ih[g]   (f32 table)
__global__ void k_build_gtab(const float* __restrict__ embed, const float* __restrict__ wih,
                             const float* __restrict__ bih, float* __restrict__ gtab) {
    int v = blockIdx.y;
    int g = blockIdx.x * 256 + threadIdx.x;   // 0..2303
    __shared__ float ev[EN];
    if (threadIdx.x < EN) ev[threadIdx.x] = embed[v * EN + threadIdx.x];
    __syncthreads();
    const float4* w4 = (const float4*)(wih + (size_t)g * EN);
    const float4* e4 = (const float4*)ev;
    float acc = bih[g];
#pragma unroll 8
    for (int i = 0; i < EN / 4; ++i) {
        float4 w = w4[i], e = e4[i];
        acc += w.x * e.x + w.y * e.y + w.z * e.z + w.w * e.w;
    }
    gtab[(size_t)v * H3N + g] = acc;
}

// ---------------- K2: persistent-weight recurrence.
// blockIdx: replica R = bid % 16 (keeps a replica's 16 WGs on one XCD per the %8
// dispatch heuristic), wg = bid / 16 owns j in [wg*48, wg*48+48).
// thread (jl, q): jl = tid>>3 (j index), q = tid&7 (k-octile of 96 elems).
// Weights for rows {j, 768+j, 1536+j}, k-segment [q*96, q*96+96) live in VGPRs.
__global__ __launch_bounds__(NTH, 2)
void k_rnn(const int* __restrict__ tokens, const float* __restrict__ whh,
           const float* __restrict__ gtab, const float* __restrict__ bhh,
           _Float16* __restrict__ hbuf, unsigned* __restrict__ ctr,
           float* __restrict__ hout) {
    const int R   = blockIdx.x & (NREP - 1);
    const int wg  = blockIdx.x >> 4;
    const int tid = threadIdx.x;
    const int jl  = tid >> 3;
    const int q   = tid & 7;
    const int j   = wg * JPW + jl;

    __shared__ int stok[BPR][TN];
    for (int i = tid; i < BPR * TN; i += NTH)
        stok[i >> 10][i & 1023] = tokens[(size_t)(R * BPR + (i >> 10)) * TN + (i & 1023)];

    // ---- load weight slice into registers (one-time): 3 gates x 48 f16x2 pairs
    f16x2 w[3][48];
#pragma unroll
    for (int g = 0; g < 3; ++g) {
        const float2* src = (const float2*)(whh + ((size_t)(g * HN + j)) * HN + q * 96);
#pragma unroll
        for (int c = 0; c < 48; ++c) {
            float2 v = src[c];
            f16x2 t2; t2[0] = (_Float16)v.x; t2[1] = (_Float16)v.y;
            w[g][c] = t2;
        }
    }

    const float bhr = bhh[j], bhz = bhh[HN + j], bhn = bhh[2 * HN + j];
    float hprev = 0.f;                      // lanes q<4 carry h(j, batch q) in f32
    _Float16* hb = hbuf + (size_t)R * (2 * BPR * HN);
    unsigned* myc = ctr + R * 32;           // 128-B spaced counters
    float xr = 0.f, xz = 0.f, xn = 0.f;
    __syncthreads();

    for (int t = 0; t < TN; ++t) {
        if (q < BPR) {                       // prefetch x-gates for batch q (L2-resident gtab)
            const float* g_ = gtab + (size_t)stok[q][t] * H3N;
            xr = g_[j]; xz = g_[HN + j]; xn = g_[2 * HN + j];
        }
        const _Float16* hin = hb + ((t & 1) ^ 1) * (BPR * HN);
        _Float16*       hot = hb + (t & 1) * (BPR * HN);

        for (int b = 0; b < BPR; ++b) {
            const f16x8* h8 = (const f16x8*)(hin + b * HN + q * 96);
            float ar = 0.f, az = 0.f, an = 0.f;
#pragma unroll
            for (int c8 = 0; c8 < 12; ++c8) {
                F16x8 hh; hh.v = h8[c8];
#pragma unroll
                for (int p = 0; p < 4; ++p) {
                    ar = fdot2(w[0][c8 * 4 + p], hh.p[p], ar);
                    az = fdot2(w[1][c8 * 4 + p], hh.p[p], az);
                    an = fdot2(w[2][c8 * 4 + p], hh.p[p], an);
                }
            }
            // reduce over the 8 k-octile lanes (butterfly; all 8 get the sum)
            ar += __shfl_xor(ar, 1, 64); ar += __shfl_xor(ar, 2, 64); ar += __shfl_xor(ar, 4, 64);
            az += __shfl_xor(az, 1, 64); az += __shfl_xor(az, 2, 64); az += __shfl_xor(az, 4, 64);
            an += __shfl_xor(an, 1, 64); an += __shfl_xor(an, 2, 64); an += __shfl_xor(an, 4, 64);

            if (q == b) {                    // lane q==b owns (j, batch b)
                const float r  = 1.f / (1.f + __expf(-(xr + ar + bhr)));
                const float z  = 1.f / (1.f + __expf(-(xz + az + bhz)));
                const float nx = xn + r * (an + bhn);
                const float n  = 1.f - 2.f / (__expf(2.f * nx) + 1.f);   // tanh
                hprev = (1.f - z) * n + z * hprev;
                hot[b * HN + j] = (_Float16)hprev;
                if (t == TN - 1) hout[(size_t)(R * BPR + b) * HN + j] = hprev;
            }
        }

        // ---- replica barrier: monotonic counter, release/acquire at agent scope
        __syncthreads();                     // all WG stores issued (waitcnt drained)
        if (tid == 0) {
            __threadfence();                 // device-visible (L2 writeback)
            __hip_atomic_fetch_add(myc, 1u, __ATOMIC_RELEASE, __HIP_MEMORY_SCOPE_AGENT);
            const unsigned tgt = (unsigned)(WGPR * (t + 1));
            while (__hip_atomic_load(myc, __ATOMIC_ACQUIRE, __HIP_MEMORY_SCOPE_AGENT) < tgt)
                __builtin_amdgcn_s_sleep(1);
            __threadfence();
        }
        __syncthreads();
    }
}

// ---------------- K3: logits + log_softmax. one block per batch, 3 waves (one per output).
__global__ void k_logits(const float* __restrict__ hfin, const float* __restrict__ wout,
                         const float* __restrict__ bout, float* __restrict__ lp) {
    const int b = blockIdx.x;
    const int o = threadIdx.x / 64;
    const int lane = threadIdx.x % 64;
    const float* hrow = hfin + (size_t)b * HN;
    const float* w = wout + (size_t)o * HN;
    float p = 0.f;
    for (int k = lane; k < HN; k += 64) p += hrow[k] * w[k];
    for (int off = 32; off > 0; off >>= 1) p += __shfl_down(p, off, 64);
    __shared__ float lg[ON];
    if (lane == 0) lg[o] = p + bout[o];
    __syncthreads();
    if (threadIdx.x == 0) {
        float m = fmaxf(lg[0], fmaxf(lg[1], lg[2]));
        float s = __expf(lg[0] - m) + __expf(lg[1] - m) + __expf(lg[2] - m);
        float ls = __logf(s);
        lp[b * ON + 0] = lg[0] - m - ls;
        lp[b * ON + 1] = lg[1] - m - ls;
        lp[b * ON + 2] = lg[2] - m - ls;
    }
}

extern "C" void kernel_launch(void* const* d_in, const int* in_sizes, int n_in,
                              void* d_out, int out_size, void* d_ws, size_t ws_size,
                              hipStream_t stream) {
    const int*   tokens = (const int*)d_in[0];
    // d_in[1] = hidden: reference zeroes it, ignored.
    const float* embed  = (const float*)d_in[2];
    const float* wih    = (const float*)d_in[3];
    const float* whh    = (const float*)d_in[4];
    const float* bih    = (const float*)d_in[5];
    const float* bhh    = (const float*)d_in[6];
    const float* wout   = (const float*)d_in[7];
    const float* bout   = (const float*)d_in[8];

    float* out = (float*)d_out;              // [B*O logprobs][B*H h_final]
    char* ws = (char*)d_ws;
    const size_t GTAB_OFF = 0;                         // 401*2304*4 = 3,695,616
    const size_t HBUF_OFF = 3695616;                   // 16*2*4*768*2 = 196,608
    const size_t CTR_OFF  = HBUF_OFF + 196608;         // 16*32*4 = 2,048
    float*    gtab = (float*)(ws + GTAB_OFF);
    _Float16* hbuf = (_Float16*)(ws + HBUF_OFF);
    unsigned* ctr  = (unsigned*)(ws + CTR_OFF);

    // zero h double-buffers and barrier counters (ws is poisoned, not re-poisoned)
    hipMemsetAsync(ws + HBUF_OFF, 0, 196608 + 2048, stream);

    hipLaunchKernelGGL(k_build_gtab, dim3(H3N / 256, VOCABN), dim3(256), 0, stream,
                       embed, wih, bih, gtab);
    hipLaunchKernelGGL(k_rnn, dim3(NREP * WGPR), dim3(NTH), 0, stream,
                       tokens, whh, gtab, bhh, hbuf, ctr, out + BN * ON);
    hipLaunchKernelGGL(k_logits, dim3(BN), dim3(192), 0, stream,
                       out + BN * ON, wout, bout, out);
}

// Round 3
// 8220.038 us; speedup vs baseline: 11.8025x; 2.2852x over previous
//
#include <hip/hip_runtime.h>

#define VOCABN 401
#define EN 256
#define HN 768
#define H3N 2304
#define ON 3
#define BN 64
#define TN 1024

// 16 replicas x 16 WGs; each WG: 48 j's, k split 8 ways, 4 batches
#define NREP 16
#define WGPR 16
#define BPR  4
#define JPW  48
#define NTH  384

typedef _Float16 f16x2 __attribute__((ext_vector_type(2)));
typedef _Float16 f16x8 __attribute__((ext_vector_type(8)));
union F16x8 { f16x8 v; f16x2 p[4]; };

__device__ __forceinline__ float fdot2(f16x2 a, f16x2 b, float c) {
#if __has_builtin(__builtin_amdgcn_fdot2)
    return __builtin_amdgcn_fdot2(a, b, c, false);
#else
    return c + (float)a[0] * (float)b[0] + (float)a[1] * (float)b[1];
#endif
}

// ---------------- K1: gtab[v][g] = dot(embed[v], W_ih[g]) + b_ih[g]
// w-stationary: 36 blocks x 256 thr; block owns 64 g-rows; thread (gl, ql):
// gl = tid>>2 owns row g0+gl, ql = tid&3 owns k-quarter (64 f32, in regs).
__global__ __launch_bounds__(256)
void k_build_gtab(const float* __restrict__ embed, const float* __restrict__ wih,
                  const float* __restrict__ bih, float* __restrict__ gtab) {
    const int g  = blockIdx.x * 64 + (threadIdx.x >> 2);
    const int ql = threadIdx.x & 3;
    float4 w[16];
    const float4* s4 = (const float4*)(wih + (size_t)g * EN + ql * 64);
#pragma unroll
    for (int i = 0; i < 16; ++i) w[i] = s4[i];
    const float bias = bih[g];
    for (int v = 0; v < VOCABN; ++v) {
        const float4* e4 = (const float4*)(embed + (size_t)v * EN + ql * 64);
        float acc = 0.f;
#pragma unroll
        for (int i = 0; i < 16; ++i) {
            float4 e = e4[i];
            acc += w[i].x * e.x + w[i].y * e.y + w[i].z * e.z + w[i].w * e.w;
        }
        acc += __shfl_xor(acc, 1, 64);
        acc += __shfl_xor(acc, 2, 64);
        if (ql == 0) gtab[(size_t)v * H3N + g] = acc + bias;
    }
}

// ---------------- K2: persistent-weight recurrence.
// h exchange: agent-scope atomic f32 stores (write-through, nothing dirty in L2),
// agent-scope atomic 8B loads into padded LDS; barrier = release fetch_add +
// RELAXED spin (no fence, no threadfence, no cache flushes).
__global__ __launch_bounds__(NTH, 1)
void k_rnn(const int* __restrict__ tokens, const float* __restrict__ whh,
           const float* __restrict__ gtab, const float* __restrict__ bhh,
           float* __restrict__ hbuf, unsigned* __restrict__ ctr,
           float* __restrict__ hout) {
    const int R   = blockIdx.x & (NREP - 1);   // bid%16 -> replica (XCD-local by %8 heuristic)
    const int wg  = blockIdx.x >> 4;
    const int tid = threadIdx.x;
    const int jl  = tid >> 3;
    const int q   = tid & 7;
    const int j   = wg * JPW + jl;

    __shared__ int stok[BPR][TN];                     // 16384 B
    __shared__ __align__(16) _Float16 hlds[32 * 112]; // [b*8+q][96 data + 16 pad] = 7168 B

    for (int i = tid; i < BPR * TN; i += NTH)
        stok[i >> 10][i & 1023] = tokens[(size_t)(R * BPR + (i >> 10)) * TN + (i & 1023)];

    // ---- one-time: weight slice -> 36 statically-indexed f16x8 (144 VGPRs)
    F16x8 w[3][12];
#pragma unroll
    for (int g = 0; g < 3; ++g) {
        const float4* s4 = (const float4*)(whh + (size_t)(g * HN + j) * HN + q * 96);
#pragma unroll
        for (int c = 0; c < 12; ++c) {
            float4 a = s4[2 * c], b4 = s4[2 * c + 1];
            F16x8 t;
            t.v[0] = (_Float16)a.x;  t.v[1] = (_Float16)a.y;
            t.v[2] = (_Float16)a.z;  t.v[3] = (_Float16)a.w;
            t.v[4] = (_Float16)b4.x; t.v[5] = (_Float16)b4.y;
            t.v[6] = (_Float16)b4.z; t.v[7] = (_Float16)b4.w;
            w[g][c] = t;
        }
    }

    const float bhr = bhh[j], bhz = bhh[HN + j], bhn = bhh[2 * HN + j];
    float* hb = hbuf + (size_t)R * (2 * BPR * HN);
    unsigned* myc = ctr + R * 32;
    // loader constants: ull word (tid + k2*384) covers h[b=k2][2*tid .. 2*tid+1]
    const int lq = tid / 48;            // its q-slot
    const int lk = 2 * tid - lq * 96;   // its k' offset within the slot
    float hprev = 0.f, xr = 0.f, xz = 0.f, xn = 0.f;
    __syncthreads();

    for (int t = 0; t < TN; ++t) {
        if (q < BPR) {                  // x-gate prefetch (L1/L2-cached gtab)
            const float* g_ = gtab + (size_t)stok[q][t] * H3N;
            xr = g_[j]; xz = g_[HN + j]; xn = g_[2 * HN + j];
        }
        // ---- h (LLC) -> LDS: 4 x 8B atomic loads per thread
        const unsigned long long* hin64 =
            (const unsigned long long*)(hb + ((t & 1) ^ 1) * (BPR * HN));
#pragma unroll
        for (int k2 = 0; k2 < 4; ++k2) {
            unsigned long long u = __hip_atomic_load(&hin64[tid + k2 * NTH],
                                                     __ATOMIC_RELAXED, __HIP_MEMORY_SCOPE_AGENT);
            union { unsigned long long u; float f[2]; } cv; cv.u = u;
            f16x2 t2; t2[0] = (_Float16)cv.f[0]; t2[1] = (_Float16)cv.f[1];
            *(f16x2*)(hlds + ((k2 << 3) + lq) * 112 + lk) = t2;
        }
        __syncthreads();

        float* hot = hb + (t & 1) * (BPR * HN);
#pragma unroll
        for (int b = 0; b < BPR; ++b) {
            const f16x8* h8 = (const f16x8*)(hlds + ((b << 3) + q) * 112);
            float ar = 0.f, az = 0.f, an = 0.f;
#pragma unroll
            for (int c = 0; c < 12; ++c) {
                F16x8 hh; hh.v = h8[c];
#pragma unroll
                for (int p = 0; p < 4; ++p) {
                    ar = fdot2(w[0][c].p[p], hh.p[p], ar);
                    az = fdot2(w[1][c].p[p], hh.p[p], az);
                    an = fdot2(w[2][c].p[p], hh.p[p], an);
                }
            }
            ar += __shfl_xor(ar, 1, 64); ar += __shfl_xor(ar, 2, 64); ar += __shfl_xor(ar, 4, 64);
            az += __shfl_xor(az, 1, 64); az += __shfl_xor(az, 2, 64); az += __shfl_xor(az, 4, 64);
            an += __shfl_xor(an, 1, 64); an += __shfl_xor(an, 2, 64); an += __shfl_xor(an, 4, 64);

            if (q == b) {
                const float r  = 1.f / (1.f + __expf(-(xr + ar + bhr)));
                const float z  = 1.f / (1.f + __expf(-(xz + az + bhz)));
                const float nx = xn + r * (an + bhn);
                const float n  = 1.f - 2.f / (__expf(2.f * nx) + 1.f);   // tanh
                hprev = (1.f - z) * n + z * hprev;
                __hip_atomic_store(&hot[b * HN + j], hprev,
                                   __ATOMIC_RELAXED, __HIP_MEMORY_SCOPE_AGENT);
                if (t == TN - 1) hout[(size_t)(R * BPR + b) * HN + j] = hprev;
            }
        }

        if (t < TN - 1) {
            __syncthreads();            // drains vmcnt: all WG atomic stores complete
            if (tid == 0) {
                __hip_atomic_fetch_add(myc, 1u, __ATOMIC_RELEASE, __HIP_MEMORY_SCOPE_AGENT);
                const unsigned tgt = (unsigned)(WGPR * (t + 1));
                while (__hip_atomic_load(myc, __ATOMIC_RELAXED, __HIP_MEMORY_SCOPE_AGENT) < tgt)
                    __builtin_amdgcn_s_sleep(2);
            }
            __syncthreads();
        }
    }
}

// ---------------- K3: logits + log_softmax
__global__ void k_logits(const float* __restrict__ hfin, const float* __restrict__ wout,
                         const float* __restrict__ bout, float* __restrict__ lp) {
    const int b = blockIdx.x;
    const int o = threadIdx.x / 64;
    const int lane = threadIdx.x % 64;
    const float* hrow = hfin + (size_t)b * HN;
    const float* w = wout + (size_t)o * HN;
    float p = 0.f;
    for (int k = lane; k < HN; k += 64) p += hrow[k] * w[k];
    for (int off = 32; off > 0; off >>= 1) p += __shfl_down(p, off, 64);
    __shared__ float lg[ON];
    if (lane == 0) lg[o] = p + bout[o];
    __syncthreads();
    if (threadIdx.x == 0) {
        float m = fmaxf(lg[0], fmaxf(lg[1], lg[2]));
        float s = __expf(lg[0] - m) + __expf(lg[1] - m) + __expf(lg[2] - m);
        float ls = __logf(s);
        lp[b * ON + 0] = lg[0] - m - ls;
        lp[b * ON + 1] = lg[1] - m - ls;
        lp[b * ON + 2] = lg[2] - m - ls;
    }
}

extern "C" void kernel_launch(void* const* d_in, const int* in_sizes, int n_in,
                              void* d_out, int out_size, void* d_ws, size_t ws_size,
                              hipStream_t stream) {
    const int*   tokens = (const int*)d_in[0];
    // d_in[1] = hidden: reference zeroes it, ignored.
    const float* embed  = (const float*)d_in[2];
    const float* wih    = (const float*)d_in[3];
    const float* whh    = (const float*)d_in[4];
    const float* bih    = (const float*)d_in[5];
    const float* bhh    = (const float*)d_in[6];
    const float* wout   = (const float*)d_in[7];
    const float* bout   = (const float*)d_in[8];

    float* out = (float*)d_out;                  // [B*O logprobs][B*H h_final]
    char* ws = (char*)d_ws;
    const size_t GTAB_OFF = 0;                   // 401*2304*4 = 3,695,616
    const size_t HBUF_OFF = 3695616;             // 16*2*3072*4 = 393,216 (f32 now)
    const size_t CTR_OFF  = HBUF_OFF + 393216;   // 16*32*4 = 2,048
    float*    gtab = (float*)(ws + GTAB_OFF);
    float*    hbuf = (float*)(ws + HBUF_OFF);
    unsigned* ctr  = (unsigned*)(ws + CTR_OFF);

    hipMemsetAsync(ws + HBUF_OFF, 0, 393216 + 2048, stream);

    hipLaunchKernelGGL(k_build_gtab, dim3(H3N / 64), dim3(256), 0, stream,
                       embed, wih, bih, gtab);
    hipLaunchKernelGGL(k_rnn, dim3(NREP * WGPR), dim3(NTH), 0, stream,
                       tokens, whh, gtab, bhh, hbuf, ctr, out + BN * ON);
    hipLaunchKernelGGL(k_logits, dim3(BN), dim3(192), 0, stream,
                       out + BN * ON, wout, bout, out);
}